// Round 5
// baseline (186.937 us; speedup 1.0000x reference)
//
#include <hip/hip_runtime.h>
#include <hip/hip_bf16.h>

// Fixed by reference setup: N=4096, D=512, C=100
#define D_DIM 512

typedef __bf16 bf16x8 __attribute__((ext_vector_type(8)));
typedef float  f32x4  __attribute__((ext_vector_type(4)));

typedef unsigned int u32;
typedef __attribute__((address_space(1))) const u32 gl_u32;
typedef __attribute__((address_space(3))) u32 lds_u32;

// async 16B/lane global->LDS DMA; LDS dest is wave-uniform base + lane*16 (HW)
__device__ __forceinline__ void async_copy16(const void* gsrc, void* ldst) {
    __builtin_amdgcn_global_load_lds((gl_u32*)gsrc, (lds_u32*)ldst, 16, 0, 0);
}

__device__ __forceinline__ unsigned short f2bf_rne(float x) {
    unsigned int u = __float_as_uint(x);
    u += 0x7FFFu + ((u >> 16) & 1u);
    return (unsigned short)(u >> 16);
}

// One wave per row. Rows [0,N): inst, [N,2N): proxy. Output contiguous at `out`.
__global__ __launch_bounds__(256) void normalize_rows(
    const float* __restrict__ inst, const float* __restrict__ proxy,
    unsigned short* __restrict__ out, int N)
{
    int row  = blockIdx.x * 4 + (threadIdx.x >> 6);
    int lane = threadIdx.x & 63;
    const float* src = (row < N) ? inst + (size_t)row * D_DIM
                                 : proxy + (size_t)(row - N) * D_DIM;
    float4 v0 = ((const float4*)src)[lane];
    float4 v1 = ((const float4*)src)[lane + 64];
    float ss = v0.x*v0.x + v0.y*v0.y + v0.z*v0.z + v0.w*v0.w
             + v1.x*v1.x + v1.y*v1.y + v1.z*v1.z + v1.w*v1.w;
    #pragma unroll
    for (int off = 1; off < 64; off <<= 1) ss += __shfl_xor(ss, off, 64);
    float inv = 1.0f / fmaxf(sqrtf(ss), 1e-8f);
    unsigned short* dst = out + (size_t)row * D_DIM;
    ushort4 o0, o1;
    o0.x = f2bf_rne(v0.x*inv); o0.y = f2bf_rne(v0.y*inv);
    o0.z = f2bf_rne(v0.z*inv); o0.w = f2bf_rne(v0.w*inv);
    o1.x = f2bf_rne(v1.x*inv); o1.y = f2bf_rne(v1.y*inv);
    o1.z = f2bf_rne(v1.z*inv); o1.w = f2bf_rne(v1.w*inv);
    ((ushort4*)dst)[lane]      = o0;
    ((ushort4*)dst)[lane + 64] = o1;
}

// A-direct outer-product GEMM + fused epilogue.
// Logical rows [0,N) = proxy (p2i), [N,2N) = inst (i2i); B cols are always inst rows.
// Block: 256 rows x 64 cols; wave: 64 rows x 64 cols = 4x4 grid of 16x16 tiles.
// A operand: loaded straight from global into VGPRs (per-wave-private rows, no
//   barrier/drain coupling; one frag covers 16 rows x one full 64B line).
// B operand: 4 KB/kit staged via global_load_lds into a 2x4KB double buffer;
//   1 DMA per wave per kit; ONE barrier per kit (its vmcnt drain sees a single
//   DMA aged by a full compute phase).
// K-loop fully unrolled so kit*64 byte advances fold into load imm offsets.
// nd layout: [p2i_num | p2i_den | i2i_num | i2i_den], each N floats, pre-zeroed.
__global__ __launch_bounds__(256, 3) void fused_scores(
    const unsigned short* __restrict__ emb,   // [2N,512] bf16: inst rows then proxy rows
    const float* __restrict__ negmask,        // [C, N]
    const int*  __restrict__ labels,          // [N]
    const float* __restrict__ temp_p,
    const float* __restrict__ margin_p,
    float* __restrict__ nd, int N)
{
    __shared__ unsigned short Bbuf0[4 * 512];   // 4 KB
    __shared__ unsigned short Bbuf1[4 * 512];   // 4 KB

    const int tid  = threadIdx.x;
    const int lane = tid & 63;
    const int wave = tid >> 6;      // 0..3
    const int quad = lane >> 4;     // 0..3
    const int l16  = lane & 15;

    const int Cbase = blockIdx.x * 64;      // B columns (inst rows)
    const int Rbase = blockIdx.y * 256;     // logical A rows
    const bool isP2I = (Rbase < N);
    const int AbaseEmb = isP2I ? (N + Rbase) : (Rbase - N);   // proxy rows at +N in emb
    const int Rw       = AbaseEmb + wave * 64;                // wave's rows in emb coords
    const int rowLoc0  = (isP2I ? Rbase : (Rbase - N)) + wave * 64;

    const float temp  = *temp_p;
    const float scale = 1.44269504088896340736f / temp;   // log2(e)/t
    const float bias  = -(*margin_p) * scale;

    const char* embB = (const char*)emb;

    // Per-lane byte offsets. A frag mi: rows Rw+mi*16+l16, k-chunk quad (16B).
    unsigned aOff[4];
    #pragma unroll
    for (int mi = 0; mi < 4; mi++)
        aOff[mi] = (unsigned)(((Rw + mi * 16 + l16) * D_DIM + quad * 8) * 2);
    // B DMA source: wave stages frag=wave (cols Cbase+wave*16+l16, k-chunk quad).
    const unsigned bOff = (unsigned)(((Cbase + wave * 16 + l16) * D_DIM + quad * 8) * 2);

    bf16x8 Acur[4], Anext[4];
    #pragma unroll
    for (int mi = 0; mi < 4; mi++)
        Acur[mi] = *(const bf16x8*)(embB + aOff[mi]);          // kit 0
    async_copy16(embB + bOff, &Bbuf0[wave * 512]);             // kit 0

    f32x4 acc[4][4] = {};   // [mi][nt] — 64 rows x 64 cols per wave

    #pragma unroll
    for (int k = 0; k < 16; k++) {
        __syncthreads();    // B(k) DMA complete block-wide (aged by prior compute)
        unsigned short* nbuf = ((k & 1) == 0) ? Bbuf1 : Bbuf0;
        const unsigned short* cbuf = ((k & 1) == 0) ? Bbuf0 : Bbuf1;
        if (k < 15) {
            async_copy16(embB + bOff + (unsigned)((k + 1) * 64), &nbuf[wave * 512]);
            #pragma unroll
            for (int mi = 0; mi < 4; mi++)
                Anext[mi] = *(const bf16x8*)(embB + aOff[mi] + (unsigned)((k + 1) * 64));
        }
        bf16x8 b[4];
        #pragma unroll
        for (int nt = 0; nt < 4; nt++)
            b[nt] = *(const bf16x8*)&cbuf[nt * 512 + lane * 8];
        #pragma unroll
        for (int mi = 0; mi < 4; mi++)
            #pragma unroll
            for (int nt = 0; nt < 4; nt++)
                acc[mi][nt] = __builtin_amdgcn_mfma_f32_16x16x32_bf16(
                    Acur[mi], b[nt], acc[mi][nt], 0, 0, 0);
        #pragma unroll
        for (int mi = 0; mi < 4; mi++) Acur[mi] = Anext[mi];
    }

    // Epilogue: zone = exp2(sim*scale+bias); per-row sums of zone and zone*mask.
    // C/D layout: col = l16, row = quad*4 + reg.
    float* numArr = nd + (isP2I ? 0 : 2 * N);
    float* denArr = numArr + N;
    #pragma unroll
    for (int mi = 0; mi < 4; mi++) {
        #pragma unroll
        for (int r = 0; r < 4; r++) {
            int row = rowLoc0 + mi * 16 + quad * 4 + r;
            int lab = labels[row];
            const float* mrow = negmask + (size_t)lab * N + Cbase + l16;
            float den = 0.f, num = 0.f;
            #pragma unroll
            for (int nt = 0; nt < 4; nt++) {
                float zone = exp2f(acc[mi][nt][r] * scale + bias);
                den += zone;
                num += zone * mrow[nt * 16];
            }
            #pragma unroll
            for (int off = 8; off > 0; off >>= 1) {
                num += __shfl_down(num, off, 16);
                den += __shfl_down(den, off, 16);
            }
            if (l16 == 0) {
                atomicAdd(&numArr[row], num);
                atomicAdd(&denArr[row], den);
            }
        }
    }
}

__global__ __launch_bounds__(256) void loss_reduce(
    const float* __restrict__ nd, const float* __restrict__ temp_p,
    float* __restrict__ out, int N)
{
    const float t = *temp_p;
    float s = 0.f;
    for (int i = threadIdx.x; i < N; i += 256) {
        s -= logf(t * nd[i]         / nd[N + i]);       // p2i
        s -= logf(t * nd[2 * N + i] / nd[3 * N + i]);   // i2i
    }
    #pragma unroll
    for (int off = 32; off > 0; off >>= 1) s += __shfl_down(s, off, 64);
    __shared__ float wss[4];
    if ((threadIdx.x & 63) == 0) wss[threadIdx.x >> 6] = s;
    __syncthreads();
    if (threadIdx.x == 0) out[0] = (wss[0] + wss[1] + wss[2] + wss[3]) / (float)N;
}

extern "C" void kernel_launch(void* const* d_in, const int* in_sizes, int n_in,
                              void* d_out, int out_size, void* d_ws, size_t ws_size,
                              hipStream_t stream)
{
    const float* inst     = (const float*)d_in[0];
    const float* proxy    = (const float*)d_in[1];
    const float* negmask  = (const float*)d_in[2];
    const int*   labels   = (const int*)d_in[3];
    const float* temp_p   = (const float*)d_in[4];
    const float* margin_p = (const float*)d_in[5];
    float* out = (float*)d_out;

    const int N = in_sizes[3];    // 4096 (D fixed at 512 per reference)

    unsigned short* emb = (unsigned short*)d_ws;          // [2N, 512] bf16
    float* nd = (float*)(emb + (size_t)2 * N * D_DIM);    // 4N floats

    hipMemsetAsync(nd, 0, sizeof(float) * 4 * N, stream);
    normalize_rows<<<2 * N / 4, 256, 0, stream>>>(inst, proxy, emb, N);
    dim3 grid(N / 64, 2 * N / 256);   // (64, 32)
    fused_scores<<<grid, 256, 0, stream>>>(emb, negmask, labels,
                                           temp_p, margin_p, nd, N);
    loss_reduce<<<1, 256, 0, stream>>>(nd, temp_p, out, N);
}

// Round 6
// 185.705 us; speedup vs baseline: 1.0066x; 1.0066x over previous
//
#include <hip/hip_runtime.h>
#include <hip/hip_bf16.h>

// Fixed by reference setup: N=4096, D=512, C=100
#define D_DIM 512
#define KSTEPS 16          // 512 / 32 (K per MFMA)
#define BM 64              // rows per block = 4 waves x 16 rows
#define BN 64              // columns per LDS tile
#define GRIDY 4            // column chunks -> grid (128, 4) = 512 blocks

typedef __bf16 bf16x8 __attribute__((ext_vector_type(8)));
typedef float  f32x4  __attribute__((ext_vector_type(4)));

__device__ __forceinline__ unsigned short f2bf_rne(float x) {
    unsigned int u = __float_as_uint(x);
    u += 0x7FFFu + ((u >> 16) & 1u);
    return (unsigned short)(u >> 16);
}

// One wave per row. Rows [0,N): inst, [N,2N): proxy -> emb contiguous.
// Blocks 0..15 additionally zero the nd/ticket scratch (4N+16 floats).
__global__ __launch_bounds__(256) void normalize_rows(
    const float* __restrict__ inst, const float* __restrict__ proxy,
    unsigned short* __restrict__ out, float* __restrict__ nd, int N)
{
    if (blockIdx.x < 16) {
        for (int i = blockIdx.x * 256 + threadIdx.x; i < 4 * N + 16; i += 4096)
            nd[i] = 0.f;
    }
    int row  = blockIdx.x * 4 + (threadIdx.x >> 6);
    int lane = threadIdx.x & 63;
    const float* src = (row < N) ? inst + (size_t)row * D_DIM
                                 : proxy + (size_t)(row - N) * D_DIM;
    float4 v0 = ((const float4*)src)[lane];
    float4 v1 = ((const float4*)src)[lane + 64];
    float ss = v0.x*v0.x + v0.y*v0.y + v0.z*v0.z + v0.w*v0.w
             + v1.x*v1.x + v1.y*v1.y + v1.z*v1.z + v1.w*v1.w;
    #pragma unroll
    for (int off = 1; off < 64; off <<= 1) ss += __shfl_xor(ss, off, 64);
    float inv = 1.0f / fmaxf(sqrtf(ss), 1e-8f);
    unsigned short* dst = out + (size_t)row * D_DIM;
    ushort4 o0, o1;
    o0.x = f2bf_rne(v0.x*inv); o0.y = f2bf_rne(v0.y*inv);
    o0.z = f2bf_rne(v0.z*inv); o0.w = f2bf_rne(v0.w*inv);
    o1.x = f2bf_rne(v1.x*inv); o1.y = f2bf_rne(v1.y*inv);
    o1.z = f2bf_rne(v1.z*inv); o1.w = f2bf_rne(v1.w*inv);
    ((ushort4*)dst)[lane]      = o0;
    ((ushort4*)dst)[lane + 64] = o1;
}

// R1 skeleton (best measured) + fragment-major conflict-free LDS + fused tail.
// Logical rows [0,N) = proxy (p2i), [N,2N) = inst (i2i); B cols always inst.
// Wave holds its 16 A-rows' full K=512 in registers (64 VGPRs); per column-tile
// stages 64 cols x 512 K of B (64 KB LDS), then 64 MFMAs with zero barriers
// inside the K loop. LDS fragment-major: frag f=(ks*4+cg) at f*1KB, lane*16B
// -> both ds_write and ds_read are base+lane*16, conflict-free (R2: measured 0).
// nd: [p2i_num | p2i_den | i2i_num | i2i_den] (4N floats) + ticket (1 uint).
// Last-finishing block computes the final scalar loss (device-scope ticket).
__global__ __launch_bounds__(256, 2) void fused_scores(
    const unsigned short* __restrict__ emb,   // [2N,512] bf16: inst then proxy
    const float* __restrict__ negmask,        // [C, N]
    const int*  __restrict__ labels,          // [N]
    const float* __restrict__ temp_p,
    const float* __restrict__ margin_p,
    float* __restrict__ nd,
    float* __restrict__ out, int N, int colsPerBlock)
{
    __shared__ unsigned short Bt[BN * D_DIM];   // 64 KB fragment-major
    __shared__ bool amLast;

    const int tid  = threadIdx.x;
    const int lane = tid & 63;
    const int wave = tid >> 6;      // 0..3
    const int quad = lane >> 4;     // 0..3
    const int l16  = lane & 15;

    const int Rbase  = blockIdx.x * BM + wave * 16;   // wave's 16 logical rows
    const bool isP2I = (Rbase < N);
    const unsigned short* Aptr = isP2I ? (emb + (size_t)(N + Rbase) * D_DIM)
                                       : (emb + (size_t)(Rbase - N) * D_DIM);
    const int rowLocal = isP2I ? Rbase : (Rbase - N);

    const float temp  = *temp_p;
    const float scale = 1.44269504088896340736f / temp;   // log2(e)/t
    const float bias  = -(*margin_p) * scale;

    // A slab resident in registers: MFMA A-layout A[m=l16][k=quad*8+j]
    bf16x8 Afrag[KSTEPS];
    {
        const unsigned short* arow = Aptr + (size_t)l16 * D_DIM + quad * 8;
        #pragma unroll
        for (int ks = 0; ks < KSTEPS; ks++)
            Afrag[ks] = *(const bf16x8*)(arow + ks * 32);
    }

    // labels for this lane's 4 output rows (C/D layout: row = quad*4 + reg)
    int lab[4];
    #pragma unroll
    for (int r = 0; r < 4; r++) lab[r] = labels[rowLocal + quad * 4 + r];

    float numAcc[4] = {0.f,0.f,0.f,0.f};
    float denAcc[4] = {0.f,0.f,0.f,0.f};

    const int j0base = blockIdx.y * colsPerBlock;
    for (int jt = 0; jt < colsPerBlock; jt += BN) {
        const int j0 = j0base + jt;
        __syncthreads();   // protect previous tile's reads
        // Stage fragment-major: frag f -> cols (f&3)*16+l16, k-chunk (f>>2)*4+quad.
        // Global side: 16 rows x 64B contiguous per instruction (full lines).
        #pragma unroll
        for (int it = 0; it < 16; it++) {
            int f  = it * 4 + wave;
            int ks = f >> 2;
            int cg = f & 3;
            const unsigned short* src =
                emb + (size_t)(j0 + cg * 16 + l16) * D_DIM + ks * 32 + quad * 8;
            *(bf16x8*)&Bt[f * 512 + lane * 8] = *(const bf16x8*)src;
        }
        __syncthreads();

        f32x4 acc[4] = {};   // 4 column groups of 16
        #pragma unroll
        for (int ks = 0; ks < KSTEPS; ks++) {
            #pragma unroll
            for (int cg = 0; cg < 4; cg++) {
                bf16x8 b = *(const bf16x8*)&Bt[(ks * 4 + cg) * 512 + lane * 8];
                acc[cg] = __builtin_amdgcn_mfma_f32_16x16x32_bf16(Afrag[ks], b, acc[cg], 0, 0, 0);
            }
        }

        // Epilogue: zone = exp2(sim*scale + bias); accumulate den and masked num
        #pragma unroll
        for (int cg = 0; cg < 4; cg++) {
            int j = j0 + cg * 16 + l16;
            #pragma unroll
            for (int r = 0; r < 4; r++) {
                float zone = exp2f(acc[cg][r] * scale + bias);
                denAcc[r] += zone;
                float m = negmask[(size_t)lab[r] * N + j];
                numAcc[r] += zone * m;
            }
        }
    }

    // Reduce across the 16 lanes sharing each output row, then atomicAdd
    float* numArr = nd + (isP2I ? 0 : 2 * N);
    float* denArr = numArr + N;
    #pragma unroll
    for (int r = 0; r < 4; r++) {
        float n = numAcc[r], d = denAcc[r];
        #pragma unroll
        for (int off = 8; off > 0; off >>= 1) {
            n += __shfl_down(n, off, 16);
            d += __shfl_down(d, off, 16);
        }
        if (l16 == 0) {
            atomicAdd(&numArr[rowLocal + quad * 4 + r], n);
            atomicAdd(&denArr[rowLocal + quad * 4 + r], d);
        }
    }

    // ---- fused final reduction: last-finishing block computes the loss ----
    __threadfence();                              // device-scope: flush our atomics
    if (tid == 0) {
        unsigned* ticket = (unsigned*)(nd + 4 * N);
        unsigned t = atomicAdd(ticket, 1u);
        amLast = (t == gridDim.x * gridDim.y - 1);
    }
    __syncthreads();
    if (amLast) {
        float s = 0.f;
        for (int i = tid; i < N; i += 256) {
            float pn = __hip_atomic_load(&nd[i],         __ATOMIC_RELAXED, __HIP_MEMORY_SCOPE_AGENT);
            float pd = __hip_atomic_load(&nd[N + i],     __ATOMIC_RELAXED, __HIP_MEMORY_SCOPE_AGENT);
            float in_ = __hip_atomic_load(&nd[2 * N + i], __ATOMIC_RELAXED, __HIP_MEMORY_SCOPE_AGENT);
            float id_ = __hip_atomic_load(&nd[3 * N + i], __ATOMIC_RELAXED, __HIP_MEMORY_SCOPE_AGENT);
            s -= logf(temp * pn / pd) + logf(temp * in_ / id_);
        }
        #pragma unroll
        for (int off = 32; off > 0; off >>= 1) s += __shfl_down(s, off, 64);
        __shared__ float wss[4];
        if ((tid & 63) == 0) wss[tid >> 6] = s;
        __syncthreads();
        if (tid == 0) out[0] = (wss[0] + wss[1] + wss[2] + wss[3]) / (float)N;
    }
}

extern "C" void kernel_launch(void* const* d_in, const int* in_sizes, int n_in,
                              void* d_out, int out_size, void* d_ws, size_t ws_size,
                              hipStream_t stream)
{
    const float* inst     = (const float*)d_in[0];
    const float* proxy    = (const float*)d_in[1];
    const float* negmask  = (const float*)d_in[2];
    const int*   labels   = (const int*)d_in[3];
    const float* temp_p   = (const float*)d_in[4];
    const float* margin_p = (const float*)d_in[5];
    float* out = (float*)d_out;

    const int N = in_sizes[3];    // 4096 (D fixed at 512 per reference)

    unsigned short* emb = (unsigned short*)d_ws;          // [2N, 512] bf16
    float* nd = (float*)(emb + (size_t)2 * N * D_DIM);    // 4N floats + ticket

    normalize_rows<<<2 * N / 4, 256, 0, stream>>>(inst, proxy, emb, nd, N);
    dim3 grid(2 * N / BM, GRIDY);   // (128, 4)
    fused_scores<<<grid, 256, 0, stream>>>(emb, negmask, labels,
                                           temp_p, margin_p, nd, out, N, N / GRIDY);
}